// Round 3
// baseline (26.643 us; speedup 1.0000x reference)
//
#include <hip/hip_runtime.h>

// Embedding gather: out[b,s,:] = W[x[b,s],:]
// x: (B=4, S=4096) int32, W: (50257, 1024) f32, out: (4,4096,1024) f32.
// Memory-bound row gather. 16B vector access, 4x-batched gathers for MLP,
// non-temporal stores (output never re-read; keep L2 for W rows).
// NOTE: __builtin_nontemporal_store needs a native vector type, not HIP float4.

typedef float f32x4 __attribute__((ext_vector_type(4)));

#define D_MODEL 1024
#define D4 (D_MODEL / 4)   // 256 x 16B per row

__global__ void embedding_gather_kernel(const int* __restrict__ x,
                                        const f32x4* __restrict__ W4,
                                        f32x4* __restrict__ out4,
                                        long long total4) {
    const long long stride = (long long)gridDim.x * blockDim.x;
    long long t = (long long)blockIdx.x * blockDim.x + threadIdx.x;

    // Main: 4 independent gathers in flight before any store.
    for (; t + 3 * stride < total4; t += 4 * stride) {
        long long t0 = t, t1 = t + stride, t2 = t + 2 * stride, t3 = t + 3 * stride;
        int r0 = x[t0 >> 8], r1 = x[t1 >> 8], r2 = x[t2 >> 8], r3 = x[t3 >> 8];
        f32x4 v0 = W4[(long long)r0 * D4 + (t0 & (D4 - 1))];
        f32x4 v1 = W4[(long long)r1 * D4 + (t1 & (D4 - 1))];
        f32x4 v2 = W4[(long long)r2 * D4 + (t2 & (D4 - 1))];
        f32x4 v3 = W4[(long long)r3 * D4 + (t3 & (D4 - 1))];
        __builtin_nontemporal_store(v0, &out4[t0]);
        __builtin_nontemporal_store(v1, &out4[t1]);
        __builtin_nontemporal_store(v2, &out4[t2]);
        __builtin_nontemporal_store(v3, &out4[t3]);
    }
    // Tail.
    for (; t < total4; t += stride) {
        int r = x[t >> 8];
        f32x4 v = W4[(long long)r * D4 + (t & (D4 - 1))];
        __builtin_nontemporal_store(v, &out4[t]);
    }
}

extern "C" void kernel_launch(void* const* d_in, const int* in_sizes, int n_in,
                              void* d_out, int out_size, void* d_ws, size_t ws_size,
                              hipStream_t stream) {
    const int*   x   = (const int*)d_in[0];     // (B*S,)
    const f32x4* W4  = (const f32x4*)d_in[1];   // (VOCAB, D4)
    f32x4*       out = (f32x4*)d_out;

    long long total4 = (long long)out_size / 4;  // 4,194,304

    const int block = 256;
    long long nblocks = (total4 + block - 1) / block;
    int grid = (int)(nblocks < 2048 ? nblocks : 2048);

    embedding_gather_kernel<<<grid, block, 0, stream>>>(x, W4, out, total4);
}

// Round 4
// 25.596 us; speedup vs baseline: 1.0409x; 1.0409x over previous
//
#include <hip/hip_runtime.h>

// Embedding gather: out[b,s,:] = W[x[b,s],:]
// x: (B=4, S=4096) int32, W: (50257, 1024) f32, out: (4,4096,1024) f32.
// One block = 4 consecutive tokens. Index loads are block-uniform -> SALU
// s_load; each thread moves one float4 per token (4 independent load/store
// pairs, fully coalesced: a block covers 4 full 4 KiB rows).

typedef float f32x4 __attribute__((ext_vector_type(4)));

#define D4 256           // float4 per 1024-float row
#define TOK_PER_BLOCK 4

__global__ __launch_bounds__(256) void embedding_gather_kernel(
        const int* __restrict__ x,
        const f32x4* __restrict__ W4,
        f32x4* __restrict__ out4) {
    const int tid = threadIdx.x;           // 0..255 -> column in row
    const int t0  = blockIdx.x * TOK_PER_BLOCK;

    // Block-uniform index loads -> scalar loads.
    const int r0 = x[t0 + 0];
    const int r1 = x[t0 + 1];
    const int r2 = x[t0 + 2];
    const int r3 = x[t0 + 3];

    // 4 independent gathers in flight, then 4 stores.
    f32x4 v0 = W4[(long long)r0 * D4 + tid];
    f32x4 v1 = W4[(long long)r1 * D4 + tid];
    f32x4 v2 = W4[(long long)r2 * D4 + tid];
    f32x4 v3 = W4[(long long)r3 * D4 + tid];

    f32x4* o = out4 + (long long)t0 * D4 + tid;
    o[0 * D4] = v0;
    o[1 * D4] = v1;
    o[2 * D4] = v2;
    o[3 * D4] = v3;
}

extern "C" void kernel_launch(void* const* d_in, const int* in_sizes, int n_in,
                              void* d_out, int out_size, void* d_ws, size_t ws_size,
                              hipStream_t stream) {
    const int*   x   = (const int*)d_in[0];     // (B*S,) = 16384 tokens
    const f32x4* W4  = (const f32x4*)d_in[1];   // (VOCAB, D4)
    f32x4*       out = (f32x4*)d_out;

    const int n_tokens = in_sizes[0];           // 16384
    const int grid = n_tokens / TOK_PER_BLOCK;  // 4096 blocks

    embedding_gather_kernel<<<grid, 256, 0, stream>>>(x, W4, out);
}

// Round 5
// 25.391 us; speedup vs baseline: 1.0493x; 1.0081x over previous
//
#include <hip/hip_runtime.h>

// Embedding gather: out[b,s,:] = W[x[b,s],:]
// x: (B=4, S=4096) int32, W: (50257, 1024) f32, out: (4,4096,1024) f32.
// One block = 8 consecutive tokens; 256 threads; index loads block-uniform
// (scalar path). 8 independent row-gathers in flight per thread, then 8
// non-temporal stores: out is never re-read, and keeping the 64 MiB output
// stream out of L2/L3 preserves L3 residency of the 196 MiB W table across
// graph replays (W fits in the 256 MiB Infinity Cache).

typedef float f32x4 __attribute__((ext_vector_type(4)));

#define D4 256           // float4 per 1024-float row
#define TOK_PER_BLOCK 8

__global__ __launch_bounds__(256) void embedding_gather_kernel(
        const int* __restrict__ x,
        const f32x4* __restrict__ W4,
        f32x4* __restrict__ out4) {
    const int tid = threadIdx.x;           // 0..255 -> column in row
    const int t0  = blockIdx.x * TOK_PER_BLOCK;

    // Block-uniform index loads -> scalar loads.
    int r[TOK_PER_BLOCK];
#pragma unroll
    for (int i = 0; i < TOK_PER_BLOCK; ++i) r[i] = x[t0 + i];

    // All gathers issued before any store (independent, deep MLP).
    f32x4 v[TOK_PER_BLOCK];
#pragma unroll
    for (int i = 0; i < TOK_PER_BLOCK; ++i)
        v[i] = W4[(long long)r[i] * D4 + tid];

    f32x4* o = out4 + (long long)t0 * D4 + tid;
#pragma unroll
    for (int i = 0; i < TOK_PER_BLOCK; ++i)
        __builtin_nontemporal_store(v[i], &o[i * D4]);
}

extern "C" void kernel_launch(void* const* d_in, const int* in_sizes, int n_in,
                              void* d_out, int out_size, void* d_ws, size_t ws_size,
                              hipStream_t stream) {
    const int*   x   = (const int*)d_in[0];     // (B*S,) = 16384 tokens
    const f32x4* W4  = (const f32x4*)d_in[1];   // (VOCAB, D4)
    f32x4*       out = (f32x4*)d_out;

    const int n_tokens = in_sizes[0];           // 16384
    const int grid = n_tokens / TOK_PER_BLOCK;  // 2048 blocks

    embedding_gather_kernel<<<grid, 256, 0, stream>>>(x, W4, out);
}